// Round 1
// baseline (398.249 us; speedup 1.0000x reference)
//
#include <hip/hip_runtime.h>
#include <hip/hip_bf16.h>

typedef _Float16 half_t;
typedef __attribute__((ext_vector_type(4))) _Float16 h4_t;
typedef __attribute__((ext_vector_type(8))) _Float16 h8_t;
typedef __attribute__((ext_vector_type(4))) float f32x4;

#define LDSS 56  // LDS row stride in halves: 112B = 16B-aligned, 2-way-conflict-free

// C[M,N] = A[M,K] @ B[K,N]; A is f32 or f16, B is f32, C is f16 or f32.
// 64x64 block tile, 4 waves (each 32x32), BK=32, mfma_f32_16x16x32_f16.
template<typename AT, typename CT>
__global__ __launch_bounds__(256) void gemm_kernel(const AT* __restrict__ A,
                                                   const float* __restrict__ B,
                                                   CT* __restrict__ C,
                                                   int M, int N, int K)
{
    __shared__ half_t Ah[64][LDSS];
    __shared__ half_t Bt[64][LDSS];  // B transposed: Bt[n][k]
    const int tid  = threadIdx.x;
    const int lane = tid & 63;
    const int wid  = tid >> 6;
    const int wm   = wid >> 1, wn = wid & 1;
    const int lr   = lane & 15, lg = lane >> 4;
    const int m0   = blockIdx.y * 64, n0 = blockIdx.x * 64;

    f32x4 acc[2][2] = {};

    for (int k0 = 0; k0 < K; k0 += 32) {
        // stage A tile (64 x 32), 4 elems/thread/iter
        #pragma unroll
        for (int i = 0; i < 2; i++) {
            int lin = tid + i * 256;          // 0..511
            int row = lin >> 3;
            int c4  = (lin & 7) << 2;
            h4_t hv;
            if constexpr (sizeof(AT) == 4) {
                const float4 v = *reinterpret_cast<const float4*>(
                    A + (size_t)(m0 + row) * K + k0 + c4);
                hv = h4_t{(half_t)v.x, (half_t)v.y, (half_t)v.z, (half_t)v.w};
            } else {
                hv = *reinterpret_cast<const h4_t*>(
                    A + (size_t)(m0 + row) * K + k0 + c4);
            }
            *reinterpret_cast<h4_t*>(&Ah[row][c4]) = hv;
        }
        // stage B tile (32 x 64) transposed into Bt[n][k]
        #pragma unroll
        for (int i = 0; i < 2; i++) {
            int lin = tid + i * 256;
            int k   = lin >> 4;               // 0..31
            int c4  = (lin & 15) << 2;        // 0..60
            const float4 v = *reinterpret_cast<const float4*>(
                B + (size_t)(k0 + k) * N + n0 + c4);
            Bt[c4 + 0][k] = (half_t)v.x;
            Bt[c4 + 1][k] = (half_t)v.y;
            Bt[c4 + 2][k] = (half_t)v.z;
            Bt[c4 + 3][k] = (half_t)v.w;
        }
        __syncthreads();

        h8_t af[2], bf[2];
        #pragma unroll
        for (int mt = 0; mt < 2; mt++)
            af[mt] = *reinterpret_cast<const h8_t*>(&Ah[wm * 32 + mt * 16 + lr][lg * 8]);
        #pragma unroll
        for (int nt = 0; nt < 2; nt++)
            bf[nt] = *reinterpret_cast<const h8_t*>(&Bt[wn * 32 + nt * 16 + lr][lg * 8]);
        #pragma unroll
        for (int mt = 0; mt < 2; mt++)
            #pragma unroll
            for (int nt = 0; nt < 2; nt++)
                acc[mt][nt] = __builtin_amdgcn_mfma_f32_16x16x32_f16(
                    af[mt], bf[nt], acc[mt][nt], 0, 0, 0);
        __syncthreads();
    }

    #pragma unroll
    for (int mt = 0; mt < 2; mt++)
        #pragma unroll
        for (int nt = 0; nt < 2; nt++)
            #pragma unroll
            for (int r = 0; r < 4; r++) {
                int row = m0 + wm * 32 + mt * 16 + lg * 4 + r;
                int col = n0 + wn * 32 + nt * 16 + lr;
                C[(size_t)row * N + col] = (CT)acc[mt][nt][r];
            }
}

// RoPE in-place on K and V half buffers [2048 rows][512 cols], pairs along head dim.
__global__ __launch_bounds__(256) void rope_kernel(half_t* __restrict__ Kh,
                                                   half_t* __restrict__ Vh,
                                                   const float* __restrict__ cs,
                                                   const float* __restrict__ sn)
{
    const int npairs = 2048 * 256;
    int gid = blockIdx.x * 256 + threadIdx.x;      // 0 .. 2*npairs-1
    half_t* buf = (gid < npairs) ? Kh : Vh;
    int pid = gid & (npairs - 1);
    int row = pid >> 8;                             // 0..2047 (b*1024+s)
    int pc  = pid & 255;                            // pair within row
    int s   = row & 1023;
    int p   = pc & 63;                              // pair within head
    float c  = cs[s * 64 + p];
    float si = sn[s * 64 + p];
    size_t base = (size_t)row * 512 + 2 * pc;
    float x0 = (float)buf[base];
    float x1 = (float)buf[base + 1];
    buf[base]     = (half_t)(x0 * c - x1 * si);
    buf[base + 1] = (half_t)(x0 * si + x1 * c);
}

// Causal GQA flash attention. Block = 64 q-rows (4 waves x 16), keys in blocks of 32.
__global__ __launch_bounds__(256) void attn_kernel(const half_t* __restrict__ Qh,
                                                   const half_t* __restrict__ Kh,
                                                   const half_t* __restrict__ Vh,
                                                   half_t* __restrict__ Yh)
{
    __shared__ half_t P_lds[4][16][LDSS];           // per-wave P tile (16 q x 32 k)
    const int tid = threadIdx.x, lane = tid & 63, wid = tid >> 6;
    const int lr = lane & 15, lg = lane >> 4;
    const int bx = blockIdx.x;
    const int qt = bx & 15;                          // 64-row q tile index
    const int h  = (bx >> 4) & 15;
    const int b  = bx >> 8;
    const int kvh = h >> 2;                          // GQA: 4 q-heads per kv-head
    const int qbase = qt * 64 + wid * 16;            // this wave's first q row (in S)
    const size_t qrow0 = (size_t)(b * 1024 + qbase);

    // Q fragments for 16 rows x 128 d, held in registers (4 k-steps of 32)
    h8_t qf[4];
    #pragma unroll
    for (int kk = 0; kk < 4; kk++)
        qf[kk] = *reinterpret_cast<const h8_t*>(
            Qh + (qrow0 + lr) * 2048 + h * 128 + kk * 32 + lg * 8);

    float m[4], l[4];
    f32x4 yacc[8] = {};
    #pragma unroll
    for (int r = 0; r < 4; r++) { m[r] = -__builtin_inff(); l[r] = 0.f; }

    const int nkb = qt * 2 + 2;                      // key blocks of 32, covers q <= qbase+63
    const float sc = 0.08838834764831845f;           // 1/sqrt(128)

    for (int kb = 0; kb < nkb; kb++) {
        const int j = kb * 32;
        const size_t krow = (size_t)(b * 1024 + j);
        // logits: S[16q x 32k] = Q(16x128) . K^T(128x32) as two 16x16 D-tiles
        f32x4 s0 = {}, s1 = {};
        #pragma unroll
        for (int kk = 0; kk < 4; kk++) {
            h8_t k0f = *reinterpret_cast<const h8_t*>(
                Kh + (krow + lr) * 512 + kvh * 128 + kk * 32 + lg * 8);
            h8_t k1f = *reinterpret_cast<const h8_t*>(
                Kh + (krow + 16 + lr) * 512 + kvh * 128 + kk * 32 + lg * 8);
            s0 = __builtin_amdgcn_mfma_f32_16x16x32_f16(qf[kk], k0f, s0, 0, 0, 0);
            s1 = __builtin_amdgcn_mfma_f32_16x16x32_f16(qf[kk], k1f, s1, 0, 0, 0);
        }
        // scale + causal mask; D layout: row=(lane>>4)*4+r, col=lane&15
        float mb[4];
        #pragma unroll
        for (int r = 0; r < 4; r++) {
            const int q = qbase + lg * 4 + r;
            float v0 = (j + lr      <= q) ? s0[r] * sc : -__builtin_inff();
            float v1 = (j + 16 + lr <= q) ? s1[r] * sc : -__builtin_inff();
            s0[r] = v0; s1[r] = v1;
            mb[r] = fmaxf(v0, v1);
        }
        #pragma unroll
        for (int off = 1; off < 16; off <<= 1)
            #pragma unroll
            for (int r = 0; r < 4; r++)
                mb[r] = fmaxf(mb[r], __shfl_xor(mb[r], off));
        // online softmax update (f32)
        float al[4], p0[4], p1[4], rs[4];
        #pragma unroll
        for (int r = 0; r < 4; r++) {
            float mn = fmaxf(m[r], mb[r]);
            al[r] = __expf(m[r] - mn);               // m=-inf only at kb=0 where mb finite
            m[r]  = mn;
            p0[r] = __expf(s0[r] - mn);
            p1[r] = __expf(s1[r] - mn);
            rs[r] = p0[r] + p1[r];
        }
        #pragma unroll
        for (int off = 1; off < 16; off <<= 1)
            #pragma unroll
            for (int r = 0; r < 4; r++)
                rs[r] += __shfl_xor(rs[r], off);
        #pragma unroll
        for (int r = 0; r < 4; r++)
            l[r] = l[r] * al[r] + rs[r];
        #pragma unroll
        for (int dt = 0; dt < 8; dt++)
            #pragma unroll
            for (int r = 0; r < 4; r++)
                yacc[dt][r] *= al[r];
        // re-layout P: D-frag -> LDS -> A-frag (wave-private buffer)
        #pragma unroll
        for (int r = 0; r < 4; r++) {
            P_lds[wid][lg * 4 + r][lr]      = (half_t)p0[r];
            P_lds[wid][lg * 4 + r][16 + lr] = (half_t)p1[r];
        }
        __syncthreads();                              // uniform trips: qt is block-level
        const h8_t pf = *reinterpret_cast<const h8_t*>(&P_lds[wid][lr][lg * 8]);
        // PV: Y(16x128) += P(16x32) . V(32x128), 8 d-tiles
        #pragma unroll
        for (int dt = 0; dt < 8; dt++) {
            h8_t vf;
            #pragma unroll
            for (int e = 0; e < 8; e++)
                vf[e] = Vh[(krow + lg * 8 + e) * 512 + kvh * 128 + dt * 16 + lr];
            yacc[dt] = __builtin_amdgcn_mfma_f32_16x16x32_f16(pf, vf, yacc[dt], 0, 0, 0);
        }
        __syncthreads();
    }

    #pragma unroll
    for (int r = 0; r < 4; r++) l[r] = 1.f / l[r];
    #pragma unroll
    for (int dt = 0; dt < 8; dt++)
        #pragma unroll
        for (int r = 0; r < 4; r++)
            Yh[(qrow0 + lg * 4 + r) * 2048 + h * 128 + dt * 16 + lr] =
                (half_t)(yacc[dt][r] * l[r]);
}

extern "C" void kernel_launch(void* const* d_in, const int* in_sizes, int n_in,
                              void* d_out, int out_size, void* d_ws, size_t ws_size,
                              hipStream_t stream) {
    const float* x  = (const float*)d_in[0];
    const float* tc = (const float*)d_in[1];
    const float* ts = (const float*)d_in[2];
    const float* wq = (const float*)d_in[3];
    const float* wk = (const float*)d_in[4];
    const float* wv = (const float*)d_in[5];
    const float* wo = (const float*)d_in[6];
    float* out = (float*)d_out;

    const int M = 2048, DIM = 2048, KVD = 512;
    half_t* Qh = (half_t*)d_ws;                 // 2048x2048 f16 = 8 MB
    half_t* Kh = Qh + (size_t)M * DIM;          // 2048x512  f16 = 2 MB
    half_t* Vh = Kh + (size_t)M * KVD;          // 2 MB
    half_t* Yh = Vh + (size_t)M * KVD;          // 8 MB   (total 20 MB of d_ws)

    dim3 blk(256);
    gemm_kernel<float, half_t><<<dim3(DIM / 64, M / 64), blk, 0, stream>>>(x, wq, Qh, M, DIM, DIM);
    gemm_kernel<float, half_t><<<dim3(KVD / 64, M / 64), blk, 0, stream>>>(x, wk, Kh, M, KVD, DIM);
    gemm_kernel<float, half_t><<<dim3(KVD / 64, M / 64), blk, 0, stream>>>(x, wv, Vh, M, KVD, DIM);
    rope_kernel<<<dim3(2 * M * 256 / 256), blk, 0, stream>>>(Kh, Vh, tc, ts);
    attn_kernel<<<dim3(2 * 16 * 16), blk, 0, stream>>>(Qh, Kh, Vh, Yh);
    gemm_kernel<half_t, float><<<dim3(DIM / 64, M / 64), blk, 0, stream>>>(Yh, wo, out, M, DIM, DIM);
}

// Round 2
// 198.523 us; speedup vs baseline: 2.0061x; 2.0061x over previous
//
#include <hip/hip_runtime.h>
#include <hip/hip_bf16.h>
#include <stdint.h>

typedef _Float16 half_t;
typedef __attribute__((ext_vector_type(2))) _Float16 h2_t;
typedef __attribute__((ext_vector_type(4))) _Float16 h4_t;
typedef __attribute__((ext_vector_type(8))) _Float16 h8_t;
typedef __attribute__((ext_vector_type(4))) float f32x4;

// async global->LDS, 16B per lane. LDS dest must be wave-uniform base (HW adds lane*16).
__device__ __forceinline__ void gload16(const void* g, void* l) {
    __builtin_amdgcn_global_load_lds(
        (const __attribute__((address_space(1))) uint32_t*)(uintptr_t)g,
        (__attribute__((address_space(3))) uint32_t*)(uint32_t)(uintptr_t)l,
        16, 0, 0);
}

// ---------------- x: f32 -> f16 ----------------
__global__ __launch_bounds__(256) void cvt_x(const float* __restrict__ x, half_t* __restrict__ xh) {
    int g = (blockIdx.x * 256 + threadIdx.x) * 8;
    float4 a = *(const float4*)(x + g);
    float4 b = *(const float4*)(x + g + 4);
    h8_t o = {(half_t)a.x,(half_t)a.y,(half_t)a.z,(half_t)a.w,
              (half_t)b.x,(half_t)b.y,(half_t)b.z,(half_t)b.w};
    *(h8_t*)(xh + g) = o;
}

// ---------------- weights: f32 [K][N] -> f16 [N][K] (transpose+convert) ----------------
__global__ __launch_bounds__(256) void wtrans(const float* __restrict__ wq, const float* __restrict__ wk,
                                              const float* __restrict__ wv, const float* __restrict__ wo,
                                              half_t* __restrict__ qt, half_t* __restrict__ kt,
                                              half_t* __restrict__ vt, half_t* __restrict__ ot) {
    __shared__ half_t T[32][36];
    int bx = blockIdx.x;
    const float* src; half_t* dst; int Nd, t;
    if (bx < 4096)      { src = wq; dst = qt; Nd = 2048; t = bx; }
    else if (bx < 5120) { src = wk; dst = kt; Nd = 512;  t = bx - 4096; }
    else if (bx < 6144) { src = wv; dst = vt; Nd = 512;  t = bx - 5120; }
    else                { src = wo; dst = ot; Nd = 2048; t = bx - 6144; }
    const int K = 2048;
    int nt = Nd >> 5;
    int ti = t / nt, tj = t % nt;          // ti: K-tile, tj: N-tile
    int r  = threadIdx.x >> 3;
    int c4 = (threadIdx.x & 7) << 2;
    float4 v = *(const float4*)(src + (size_t)(ti*32 + r) * Nd + tj*32 + c4);
    T[r][c4+0] = (half_t)v.x; T[r][c4+1] = (half_t)v.y;
    T[r][c4+2] = (half_t)v.z; T[r][c4+3] = (half_t)v.w;
    __syncthreads();
    h4_t o = {T[c4+0][r], T[c4+1][r], T[c4+2][r], T[c4+3][r]};
    *(h4_t*)(dst + (size_t)(tj*32 + r) * K + ti*32 + c4) = o;
}

// ---------------- GEMM: C = A[M][K] @ W^T, W stored [N][K] f16 (m97 structure) ----------------
// 128x128 tile, BK=32, 4 waves (2x2), each wave 64x64 = 4x4 16x16x32 frags.
// QKV=1: fused Q/K/V projection (NB=24: 16 q-blocks + 4 k + 4 v).
template<int QKV, typename CT>
__global__ __launch_bounds__(256) void gemm128(const half_t* __restrict__ A,
                                               const half_t* __restrict__ Bq,
                                               const half_t* __restrict__ Bk,
                                               const half_t* __restrict__ Bv,
                                               CT* __restrict__ Cq,
                                               half_t* __restrict__ Ck,
                                               half_t* __restrict__ Cv,
                                               int NB, int K) {
    __shared__ half_t Ah[128][32];
    __shared__ half_t Bh[128][32];
    const int tid = threadIdx.x, lane = tid & 63, wid = tid >> 6;
    const int lr = lane & 15, lg = lane >> 4;
    const int wm = wid >> 1, wn = wid & 1;
    const int nwg = gridDim.x, bid = blockIdx.x;
    const int swz = (bid & 7) * (nwg >> 3) + (bid >> 3);   // XCD swizzle (nwg % 8 == 0)
    const int bm = swz / NB, bn = swz % NB;
    const int m0 = bm * 128;

    const half_t* W; CT* Cc; int cs, col0;
    if constexpr (QKV) {
        if (bn < 16)      { W = Bq + (size_t)bn * 128 * K;        Cc = Cq;       cs = 2048; col0 = bn * 128; }
        else if (bn < 20) { W = Bk + (size_t)(bn - 16) * 128 * K; Cc = (CT*)Ck;  cs = 512;  col0 = (bn - 16) * 128; }
        else              { W = Bv + (size_t)(bn - 20) * 128 * K; Cc = (CT*)Cv;  cs = 512;  col0 = (bn - 20) * 128; }
    } else {
        W = Bq + (size_t)bn * 128 * K; Cc = Cq; cs = NB * 128; col0 = bn * 128;
    }

    const half_t* Arow = A + (size_t)m0 * K;
    f32x4 acc[4][4] = {};

    for (int k0 = 0; k0 < K; k0 += 32) {
        #pragma unroll
        for (int c = 0; c < 2; c++) {
            const int chunk = c * 4 + wid;                 // 0..7, wave-uniform
            const int o     = (chunk << 10) + lane * 16;   // byte offset in 8KB tile
            const int row   = o >> 6;                      // 16 rows per chunk
            const int colh  = (o & 63) >> 1;               // halves within row
            gload16(Arow + (size_t)row * K + k0 + colh, (char*)&Ah[0][0] + (chunk << 10));
            gload16(W    + (size_t)row * K + k0 + colh, (char*)&Bh[0][0] + (chunk << 10));
        }
        __syncthreads();
        h8_t af[4], bf[4];
        #pragma unroll
        for (int i = 0; i < 4; i++) {
            af[i] = *(const h8_t*)(&Ah[wm * 64 + i * 16 + lr][lg * 8]);
            bf[i] = *(const h8_t*)(&Bh[wn * 64 + i * 16 + lr][lg * 8]);
        }
        #pragma unroll
        for (int mi = 0; mi < 4; mi++)
            #pragma unroll
            for (int ni = 0; ni < 4; ni++)
                acc[mi][ni] = __builtin_amdgcn_mfma_f32_16x16x32_f16(af[mi], bf[ni], acc[mi][ni], 0, 0, 0);
        __syncthreads();
    }

    #pragma unroll
    for (int mi = 0; mi < 4; mi++)
        #pragma unroll
        for (int ni = 0; ni < 4; ni++)
            #pragma unroll
            for (int r = 0; r < 4; r++) {
                int row = m0 + wm * 64 + mi * 16 + lg * 4 + r;
                int col = col0 + wn * 64 + ni * 16 + lr;
                Cc[(size_t)row * cs + col] = (CT)acc[mi][ni][r];
            }
}

// ---------------- RoPE on K, in place (f16 [2048][512]) ----------------
__global__ __launch_bounds__(256) void rope_k(half_t* __restrict__ Kh, const float* __restrict__ cs,
                                              const float* __restrict__ sn) {
    int gid = blockIdx.x * 256 + threadIdx.x;    // 2048 rows * 256 pairs
    int row = gid >> 8;
    int pc  = gid & 255;
    int s   = row & 1023;
    int p   = pc & 63;
    float c = cs[s * 64 + p], si = sn[s * 64 + p];
    h2_t v = *(h2_t*)(Kh + (size_t)row * 512 + 2 * pc);
    float x0 = (float)v[0], x1 = (float)v[1];
    h2_t o = {(half_t)(x0 * c - x1 * si), (half_t)(x0 * si + x1 * c)};
    *(h2_t*)(Kh + (size_t)row * 512 + 2 * pc) = o;
}

// ---------------- RoPE on V + transpose: Vh [2048][512] -> Vt [512][2048] ----------------
__global__ __launch_bounds__(256) void rope_v(const half_t* __restrict__ Vh, half_t* __restrict__ Vt,
                                              const float* __restrict__ cs, const float* __restrict__ sn) {
    int gid = blockIdx.x * 256 + threadIdx.x;
    int col = gid & 2047;          // b*1024+s  (lane-contiguous -> coalesced Vt writes)
    int dp  = gid >> 11;           // 0..255: global d-pair
    int s   = col & 1023;
    int p   = dp & 63;
    float c = cs[s * 64 + p], si = sn[s * 64 + p];
    h2_t v = *(const h2_t*)(Vh + (size_t)col * 512 + 2 * dp);
    float x0 = (float)v[0], x1 = (float)v[1];
    Vt[(size_t)(2 * dp)     * 2048 + col] = (half_t)(x0 * c - x1 * si);
    Vt[(size_t)(2 * dp + 1) * 2048 + col] = (half_t)(x0 * si + x1 * c);
}

// ---------------- causal GQA flash attention, 1 wave per 16 q-rows ----------------
// K row-major [2048][512]; V transposed [512][2048] -> all frags are contiguous h8 global loads.
__global__ __launch_bounds__(64) void attn2(const half_t* __restrict__ Qh, const half_t* __restrict__ Kh,
                                            const half_t* __restrict__ Vt, half_t* __restrict__ Yh) {
    __shared__ half_t P[16][72];   // pad 72: 2-way-free on b128 reads
    const int lane = threadIdx.x;
    const int lr = lane & 15, lg = lane >> 4;
    const int bx = blockIdx.x;
    const int bh = bx & 31;
    const int b  = bh >> 4, h = bh & 15;
    const int qt = 63 - (bx >> 5);           // longest q-tiles dispatch first
    const int kvh = h >> 2;
    const int qbase = qt * 16;
    const size_t qrow0 = (size_t)(b * 1024 + qbase);
    const size_t kbase = (size_t)b * 1024;

    const float sc = 0.08838834764831845f;   // 1/sqrt(128)
    h8_t qf[4];
    #pragma unroll
    for (int kk = 0; kk < 4; kk++) {
        qf[kk] = *(const h8_t*)(Qh + (qrow0 + lr) * 2048 + h * 128 + kk * 32 + lg * 8);
        qf[kk] = qf[kk] * (half_t)sc;        // fold scale into Q once
    }

    float m[4], l[4];
    f32x4 yacc[8] = {};
    #pragma unroll
    for (int r = 0; r < 4; r++) { m[r] = -1e30f; l[r] = 0.f; }

    const int nkb = (qt >> 2) + 1;           // 64-key blocks

    for (int kb = 0; kb < nkb; kb++) {
        const int j = kb * 64;
        f32x4 st[4] = {};
        #pragma unroll
        for (int t = 0; t < 4; t++)
            #pragma unroll
            for (int kk = 0; kk < 4; kk++) {
                h8_t kf = *(const h8_t*)(Kh + (kbase + j + t * 16 + lr) * 512 + kvh * 128 + kk * 32 + lg * 8);
                st[t] = __builtin_amdgcn_mfma_f32_16x16x32_f16(qf[kk], kf, st[t], 0, 0, 0);
            }
        if (kb == nkb - 1) {                 // only the last block straddles the diagonal
            #pragma unroll
            for (int t = 0; t < 4; t++)
                #pragma unroll
                for (int r = 0; r < 4; r++) {
                    int q = qbase + lg * 4 + r;
                    if (j + t * 16 + lr > q) st[t][r] = -1e30f;
                }
        }
        float mb[4];
        #pragma unroll
        for (int r = 0; r < 4; r++)
            mb[r] = fmaxf(fmaxf(st[0][r], st[1][r]), fmaxf(st[2][r], st[3][r]));
        #pragma unroll
        for (int off = 1; off < 16; off <<= 1)
            #pragma unroll
            for (int r = 0; r < 4; r++)
                mb[r] = fmaxf(mb[r], __shfl_xor(mb[r], off));
        float al[4];
        #pragma unroll
        for (int r = 0; r < 4; r++) {
            float mn = fmaxf(m[r], mb[r]);
            al[r] = __expf(m[r] - mn);
            m[r]  = mn;
        }
        float rs[4] = {0.f, 0.f, 0.f, 0.f};
        #pragma unroll
        for (int t = 0; t < 4; t++)
            #pragma unroll
            for (int r = 0; r < 4; r++) {
                float p = __expf(st[t][r] - m[r]);
                st[t][r] = p;
                rs[r] += p;
            }
        #pragma unroll
        for (int off = 1; off < 16; off <<= 1)
            #pragma unroll
            for (int r = 0; r < 4; r++)
                rs[r] += __shfl_xor(rs[r], off);
        #pragma unroll
        for (int r = 0; r < 4; r++) l[r] = l[r] * al[r] + rs[r];
        #pragma unroll
        for (int dt = 0; dt < 8; dt++)
            #pragma unroll
            for (int r = 0; r < 4; r++)
                yacc[dt][r] *= al[r];
        // P: D-frag -> LDS -> A-frag (wave-private, no barrier needed)
        #pragma unroll
        for (int t = 0; t < 4; t++)
            #pragma unroll
            for (int r = 0; r < 4; r++)
                P[lg * 4 + r][t * 16 + lr] = (half_t)st[t][r];
        h8_t pf0 = *(const h8_t*)(&P[lr][lg * 8]);
        h8_t pf1 = *(const h8_t*)(&P[lr][32 + lg * 8]);
        #pragma unroll
        for (int dt = 0; dt < 8; dt++) {
            const half_t* vrow = Vt + (size_t)(kvh * 128 + dt * 16 + lr) * 2048 + kbase + j;
            h8_t v0 = *(const h8_t*)(vrow + lg * 8);
            h8_t v1 = *(const h8_t*)(vrow + 32 + lg * 8);
            yacc[dt] = __builtin_amdgcn_mfma_f32_16x16x32_f16(pf0, v0, yacc[dt], 0, 0, 0);
            yacc[dt] = __builtin_amdgcn_mfma_f32_16x16x32_f16(pf1, v1, yacc[dt], 0, 0, 0);
        }
    }

    #pragma unroll
    for (int r = 0; r < 4; r++) l[r] = 1.0f / l[r];
    #pragma unroll
    for (int dt = 0; dt < 8; dt++)
        #pragma unroll
        for (int r = 0; r < 4; r++)
            Yh[(qrow0 + lg * 4 + r) * 2048 + h * 128 + dt * 16 + lr] = (half_t)(yacc[dt][r] * l[r]);
}

extern "C" void kernel_launch(void* const* d_in, const int* in_sizes, int n_in,
                              void* d_out, int out_size, void* d_ws, size_t ws_size,
                              hipStream_t stream) {
    const float* x  = (const float*)d_in[0];
    const float* tc = (const float*)d_in[1];
    const float* ts = (const float*)d_in[2];
    const float* wq = (const float*)d_in[3];
    const float* wk = (const float*)d_in[4];
    const float* wv = (const float*)d_in[5];
    const float* wo = (const float*)d_in[6];
    float* out = (float*)d_out;

    const size_t MD = 2048ull * 2048, MK = 2048ull * 512;
    half_t* Xh  = (half_t*)d_ws;        // 8 MB
    half_t* Qh  = Xh  + MD;             // 8 MB
    half_t* Kh  = Qh  + MD;             // 2 MB
    half_t* Vh  = Kh  + MK;             // 2 MB
    half_t* Vt  = Vh  + MK;             // 2 MB
    half_t* Yh  = Vt  + MK;             // 8 MB
    half_t* wqt = Yh  + MD;             // 8 MB
    half_t* wkt = wqt + MD;             // 2 MB
    half_t* wvt = wkt + MK;             // 2 MB
    half_t* wot = wvt + MK;             // 8 MB  (total ~42 MB)

    cvt_x <<<2048, 256, 0, stream>>>(x, Xh);
    wtrans<<<10240, 256, 0, stream>>>(wq, wk, wv, wo, wqt, wkt, wvt, wot);
    gemm128<1, half_t><<<384, 256, 0, stream>>>(Xh, wqt, wkt, wvt, Qh, Kh, Vh, 24, 2048);
    rope_k<<<2048, 256, 0, stream>>>(Kh, tc, ts);
    rope_v<<<2048, 256, 0, stream>>>(Vh, Vt, tc, ts);
    attn2 <<<2048, 64, 0, stream>>>(Qh, Kh, Vt, Yh);
    gemm128<0, float><<<256, 256, 0, stream>>>(Yh, wot, nullptr, nullptr, out, nullptr, nullptr, 16, 2048);
}

// Round 3
// 159.692 us; speedup vs baseline: 2.4939x; 1.2432x over previous
//
#include <hip/hip_runtime.h>
#include <hip/hip_bf16.h>
#include <stdint.h>

typedef _Float16 half_t;
typedef __attribute__((ext_vector_type(2))) _Float16 h2_t;
typedef __attribute__((ext_vector_type(4))) _Float16 h4_t;
typedef __attribute__((ext_vector_type(8))) _Float16 h8_t;
typedef __attribute__((ext_vector_type(4))) float f32x4;

// async global->LDS, 16B per lane. LDS dest must be wave-uniform base (HW adds lane*16).
__device__ __forceinline__ void gload16(const void* g, void* l) {
    __builtin_amdgcn_global_load_lds(
        (const __attribute__((address_space(1))) uint32_t*)(uintptr_t)g,
        (__attribute__((address_space(3))) uint32_t*)(uint32_t)(uintptr_t)l,
        16, 0, 0);
}

// ---------------- x: f32 -> f16 ----------------
__global__ __launch_bounds__(256) void cvt_x(const float* __restrict__ x, half_t* __restrict__ xh) {
    int g = (blockIdx.x * 256 + threadIdx.x) * 8;
    float4 a = *(const float4*)(x + g);
    float4 b = *(const float4*)(x + g + 4);
    h8_t o = {(half_t)a.x,(half_t)a.y,(half_t)a.z,(half_t)a.w,
              (half_t)b.x,(half_t)b.y,(half_t)b.z,(half_t)b.w};
    *(h8_t*)(xh + g) = o;
}

// ---------------- weights: f32 [K][N] -> f16 [N][K] (transpose+convert) ----------------
__global__ __launch_bounds__(256) void wtrans(const float* __restrict__ wq, const float* __restrict__ wk,
                                              const float* __restrict__ wv, const float* __restrict__ wo,
                                              half_t* __restrict__ qt, half_t* __restrict__ kt,
                                              half_t* __restrict__ vt, half_t* __restrict__ ot) {
    __shared__ half_t T[32][36];
    int bx = blockIdx.x;
    const float* src; half_t* dst; int Nd, t;
    if (bx < 4096)      { src = wq; dst = qt; Nd = 2048; t = bx; }
    else if (bx < 5120) { src = wk; dst = kt; Nd = 512;  t = bx - 4096; }
    else if (bx < 6144) { src = wv; dst = vt; Nd = 512;  t = bx - 5120; }
    else                { src = wo; dst = ot; Nd = 2048; t = bx - 6144; }
    const int K = 2048;
    int nt = Nd >> 5;
    int ti = t / nt, tj = t % nt;          // ti: K-tile, tj: N-tile
    int r  = threadIdx.x >> 3;
    int c4 = (threadIdx.x & 7) << 2;
    float4 v = *(const float4*)(src + (size_t)(ti*32 + r) * Nd + tj*32 + c4);
    T[r][c4+0] = (half_t)v.x; T[r][c4+1] = (half_t)v.y;
    T[r][c4+2] = (half_t)v.z; T[r][c4+3] = (half_t)v.w;
    __syncthreads();
    h4_t o = {T[c4+0][r], T[c4+1][r], T[c4+2][r], T[c4+3][r]};
    *(h4_t*)(dst + (size_t)(tj*32 + r) * K + ti*32 + c4) = o;
}

// ---------------- GEMM: C = A[M][K] @ W^T, W stored [N][K] f16 ----------------
// 128x128 tile, BK=64, 4 waves (2x2), each wave 64x64 = 4x4 16x16x32 frags.
template<int QKV, typename CT>
__global__ __launch_bounds__(256) void gemm128(const half_t* __restrict__ A,
                                               const half_t* __restrict__ Bq,
                                               const half_t* __restrict__ Bk,
                                               const half_t* __restrict__ Bv,
                                               CT* __restrict__ Cq,
                                               half_t* __restrict__ Ck,
                                               half_t* __restrict__ Cv,
                                               int NB, int K) {
    __shared__ half_t Ah[128 * 64];
    __shared__ half_t Bh[128 * 64];
    const int tid = threadIdx.x, lane = tid & 63, wid = tid >> 6;
    const int lr = lane & 15, lg = lane >> 4;
    const int wm = wid >> 1, wn = wid & 1;
    const int nwg = gridDim.x, bid = blockIdx.x;
    const int swz = (bid & 7) * (nwg >> 3) + (bid >> 3);   // XCD swizzle (nwg % 8 == 0)
    const int bm = swz / NB, bn = swz % NB;
    const int m0 = bm * 128;

    const half_t* W; CT* Cc; int cs, col0;
    if constexpr (QKV) {
        if (bn < 16)      { W = Bq + (size_t)bn * 128 * K;        Cc = Cq;       cs = 2048; col0 = bn * 128; }
        else if (bn < 20) { W = Bk + (size_t)(bn - 16) * 128 * K; Cc = (CT*)Ck;  cs = 512;  col0 = (bn - 16) * 128; }
        else              { W = Bv + (size_t)(bn - 20) * 128 * K; Cc = (CT*)Cv;  cs = 512;  col0 = (bn - 20) * 128; }
    } else {
        W = Bq + (size_t)bn * 128 * K; Cc = Cq; cs = NB * 128; col0 = bn * 128;
    }

    const half_t* Arow = A + (size_t)m0 * K;
    f32x4 acc[4][4] = {};

    for (int k0 = 0; k0 < K; k0 += 64) {
        #pragma unroll
        for (int c = 0; c < 4; c++) {
            const int chunk = c * 4 + wid;                 // 0..15, wave-uniform
            const int o     = (chunk << 10) + lane * 16;   // byte offset in 16KB tile
            const int row   = o >> 7;                      // 8 rows per chunk
            const int colh  = (o & 127) >> 1;
            gload16(Arow + (size_t)row * K + k0 + colh, (char*)Ah + (chunk << 10));
            gload16(W    + (size_t)row * K + k0 + colh, (char*)Bh + (chunk << 10));
        }
        __syncthreads();
        h8_t af[2][4], bf[2][4];
        #pragma unroll
        for (int kk = 0; kk < 2; kk++)
            #pragma unroll
            for (int i = 0; i < 4; i++) {
                af[kk][i] = *(const h8_t*)(Ah + (wm * 64 + i * 16 + lr) * 64 + kk * 32 + lg * 8);
                bf[kk][i] = *(const h8_t*)(Bh + (wn * 64 + i * 16 + lr) * 64 + kk * 32 + lg * 8);
            }
        #pragma unroll
        for (int kk = 0; kk < 2; kk++)
            #pragma unroll
            for (int mi = 0; mi < 4; mi++)
                #pragma unroll
                for (int ni = 0; ni < 4; ni++)
                    acc[mi][ni] = __builtin_amdgcn_mfma_f32_16x16x32_f16(af[kk][mi], bf[kk][ni], acc[mi][ni], 0, 0, 0);
        __syncthreads();
    }

    #pragma unroll
    for (int mi = 0; mi < 4; mi++)
        #pragma unroll
        for (int ni = 0; ni < 4; ni++)
            #pragma unroll
            for (int r = 0; r < 4; r++) {
                int row = m0 + wm * 64 + mi * 16 + lg * 4 + r;
                int col = col0 + wn * 64 + ni * 16 + lr;
                Cc[(size_t)row * cs + col] = (CT)acc[mi][ni][r];
            }
}

// ---------------- RoPE on K, in place (f16 [2048][512]) ----------------
__global__ __launch_bounds__(256) void rope_k(half_t* __restrict__ Kh, const float* __restrict__ cs,
                                              const float* __restrict__ sn) {
    int gid = blockIdx.x * 256 + threadIdx.x;    // 2048 rows * 256 pairs
    int row = gid >> 8;
    int pc  = gid & 255;
    int s   = row & 1023;
    int p   = pc & 63;
    float c = cs[s * 64 + p], si = sn[s * 64 + p];
    h2_t v = *(h2_t*)(Kh + (size_t)row * 512 + 2 * pc);
    float x0 = (float)v[0], x1 = (float)v[1];
    h2_t o = {(half_t)(x0 * c - x1 * si), (half_t)(x0 * si + x1 * c)};
    *(h2_t*)(Kh + (size_t)row * 512 + 2 * pc) = o;
}

// ---------------- RoPE on V + transpose: Vh [2048][512] -> Vt [512][2048] ----------------
__global__ __launch_bounds__(256) void rope_v(const half_t* __restrict__ Vh, half_t* __restrict__ Vt,
                                              const float* __restrict__ cs, const float* __restrict__ sn) {
    int gid = blockIdx.x * 256 + threadIdx.x;
    int col = gid & 2047;          // b*1024+s  (lane-contiguous -> coalesced Vt writes)
    int dp  = gid >> 11;           // 0..255: global d-pair
    int s   = col & 1023;
    int p   = dp & 63;
    float c = cs[s * 64 + p], si = sn[s * 64 + p];
    h2_t v = *(const h2_t*)(Vh + (size_t)col * 512 + 2 * dp);
    float x0 = (float)v[0], x1 = (float)v[1];
    Vt[(size_t)(2 * dp)     * 2048 + col] = (half_t)(x0 * c - x1 * si);
    Vt[(size_t)(2 * dp + 1) * 2048 + col] = (half_t)(x0 * si + x1 * c);
}

// ---------------- causal GQA flash attention, 4 waves x 16 q-rows, KVBLK=64 ----------------
// K-tile [64][128] and V^T-tile [128][64] staged in LDS (XOR-swizzled via pre-swizzled
// global source, linear global_load_lds dest). bid%8 = (b,kvh) -> XCD L2 locality.
__global__ __launch_bounds__(256) void attn3(const half_t* __restrict__ Qh, const half_t* __restrict__ Kh,
                                             const half_t* __restrict__ Vt, half_t* __restrict__ Yh) {
    __shared__ half_t Ktile[64 * 128];   // 16KB, swizzled: byte = row*256 + (colb ^ ((row&7)<<4))
    __shared__ half_t Vtile[128 * 64];   // 16KB, swizzled: byte = row*128 + (colb ^ ((row&7)<<4))
    __shared__ half_t Pl[4][16][72];     // per-wave P relayout

    const int tid = threadIdx.x, lane = tid & 63, wid = tid >> 6;
    const int lr = lane & 15, lg = lane >> 4;
    const int bx = blockIdx.x;
    const int g  = bx & 7;               // (b,kvh) group -> same XCD (round-robin dispatch)
    const int local = bx >> 3;           // 0..63
    const int b = g >> 2, kvh = g & 3;
    const int h = kvh * 4 + (local & 3);
    const int qt = 15 - (local >> 2);    // longest q-tiles first within each XCD
    const int nkb = qt + 1;
    const int qbase = qt * 64 + wid * 16;
    const size_t qrow0 = (size_t)(b * 1024 + qbase);
    const size_t kbase = (size_t)b * 1024;

    const float sc = 0.08838834764831845f;   // 1/sqrt(128)
    h8_t qf[4];
    #pragma unroll
    for (int kk = 0; kk < 4; kk++) {
        qf[kk] = *(const h8_t*)(Qh + (qrow0 + lr) * 2048 + h * 128 + kk * 32 + lg * 8);
        qf[kk] = qf[kk] * (half_t)sc;
    }

    float m[4], l[4];
    f32x4 yacc[8] = {};
    #pragma unroll
    for (int r = 0; r < 4; r++) { m[r] = -1e30f; l[r] = 0.f; }

    for (int kb = 0; kb < nkb; kb++) {
        const int j = kb * 64;
        __syncthreads();                 // all waves done with previous tiles
        #pragma unroll
        for (int c = 0; c < 4; c++) {
            const int chunk = wid * 4 + c;             // wave-uniform
            const int o = (chunk << 10) + lane * 16;   // byte offset in 16KB tile
            { // K: 8KB tile rows of 256B
              const int row  = o >> 8;
              const int colb = (o & 255) ^ ((row & 7) << 4);
              gload16(Kh + (kbase + j + row) * 512 + kvh * 128 + (colb >> 1),
                      (char*)Ktile + (chunk << 10)); }
            { // V^T: rows of 128B
              const int row  = o >> 7;
              const int colb = (o & 127) ^ ((row & 7) << 4);
              gload16(Vt + (size_t)(kvh * 128 + row) * 2048 + kbase + j + (colb >> 1),
                      (char*)Vtile + (chunk << 10)); }
        }
        __syncthreads();                 // drains global_load_lds (compiler vmcnt(0))

        // QK^T: S[16 x 64] from LDS K tile
        f32x4 st[4] = {};
        #pragma unroll
        for (int t = 0; t < 4; t++)
            #pragma unroll
            for (int kk = 0; kk < 4; kk++) {
                const int row = t * 16 + lr;
                const int cb  = (kk * 64 + lg * 16) ^ ((lr & 7) << 4);
                h8_t kf = *(const h8_t*)((const char*)Ktile + row * 256 + cb);
                st[t] = __builtin_amdgcn_mfma_f32_16x16x32_f16(qf[kk], kf, st[t], 0, 0, 0);
            }
        if (kb == nkb - 1) {             // only the diagonal block needs masking
            #pragma unroll
            for (int t = 0; t < 4; t++)
                #pragma unroll
                for (int r = 0; r < 4; r++) {
                    int q = qbase + lg * 4 + r;
                    if (j + t * 16 + lr > q) st[t][r] = -1e30f;
                }
        }
        // online softmax (f32), 16-lane groups
        float mb[4];
        #pragma unroll
        for (int r = 0; r < 4; r++)
            mb[r] = fmaxf(fmaxf(st[0][r], st[1][r]), fmaxf(st[2][r], st[3][r]));
        #pragma unroll
        for (int off = 1; off < 16; off <<= 1)
            #pragma unroll
            for (int r = 0; r < 4; r++)
                mb[r] = fmaxf(mb[r], __shfl_xor(mb[r], off));
        float al[4];
        #pragma unroll
        for (int r = 0; r < 4; r++) {
            float mn = fmaxf(m[r], mb[r]);
            al[r] = __expf(m[r] - mn);
            m[r]  = mn;
        }
        float rs[4] = {0.f, 0.f, 0.f, 0.f};
        #pragma unroll
        for (int t = 0; t < 4; t++)
            #pragma unroll
            for (int r = 0; r < 4; r++) {
                float p = __expf(st[t][r] - m[r]);
                st[t][r] = p;
                rs[r] += p;
            }
        #pragma unroll
        for (int off = 1; off < 16; off <<= 1)
            #pragma unroll
            for (int r = 0; r < 4; r++)
                rs[r] += __shfl_xor(rs[r], off);
        #pragma unroll
        for (int r = 0; r < 4; r++) l[r] = l[r] * al[r] + rs[r];
        #pragma unroll
        for (int dt = 0; dt < 8; dt++)
            #pragma unroll
            for (int r = 0; r < 4; r++)
                yacc[dt][r] *= al[r];
        // P: D-frag -> per-wave LDS -> A-frag (no cross-wave barrier needed)
        #pragma unroll
        for (int t = 0; t < 4; t++)
            #pragma unroll
            for (int r = 0; r < 4; r++)
                Pl[wid][lg * 4 + r][t * 16 + lr] = (half_t)st[t][r];
        h8_t pa0 = *(const h8_t*)(&Pl[wid][lr][lg * 8]);
        h8_t pa1 = *(const h8_t*)(&Pl[wid][lr][32 + lg * 8]);
        // PV: Y(16x128) += P(16x64) . V(64x128) from LDS V^T tile
        #pragma unroll
        for (int dt = 0; dt < 8; dt++) {
            const int row = dt * 16 + lr;
            const int cb0 = (lg * 16) ^ ((lr & 7) << 4);
            const int cb1 = (64 + lg * 16) ^ ((lr & 7) << 4);
            h8_t v0 = *(const h8_t*)((const char*)Vtile + row * 128 + cb0);
            h8_t v1 = *(const h8_t*)((const char*)Vtile + row * 128 + cb1);
            yacc[dt] = __builtin_amdgcn_mfma_f32_16x16x32_f16(pa0, v0, yacc[dt], 0, 0, 0);
            yacc[dt] = __builtin_amdgcn_mfma_f32_16x16x32_f16(pa1, v1, yacc[dt], 0, 0, 0);
        }
    }

    #pragma unroll
    for (int r = 0; r < 4; r++) l[r] = 1.0f / l[r];
    #pragma unroll
    for (int dt = 0; dt < 8; dt++)
        #pragma unroll
        for (int r = 0; r < 4; r++)
            Yh[(qrow0 + lg * 4 + r) * 2048 + h * 128 + dt * 16 + lr] = (half_t)(yacc[dt][r] * l[r]);
}

extern "C" void kernel_launch(void* const* d_in, const int* in_sizes, int n_in,
                              void* d_out, int out_size, void* d_ws, size_t ws_size,
                              hipStream_t stream) {
    const float* x  = (const float*)d_in[0];
    const float* tc = (const float*)d_in[1];
    const float* ts = (const float*)d_in[2];
    const float* wq = (const float*)d_in[3];
    const float* wk = (const float*)d_in[4];
    const float* wv = (const float*)d_in[5];
    const float* wo = (const float*)d_in[6];
    float* out = (float*)d_out;

    const size_t MD = 2048ull * 2048, MK = 2048ull * 512;
    half_t* Xh  = (half_t*)d_ws;        // 8 MB
    half_t* Qh  = Xh  + MD;             // 8 MB
    half_t* Kh  = Qh  + MD;             // 2 MB
    half_t* Vh  = Kh  + MK;             // 2 MB
    half_t* Vt  = Vh  + MK;             // 2 MB
    half_t* Yh  = Vt  + MK;             // 8 MB
    half_t* wqt = Yh  + MD;             // 8 MB
    half_t* wkt = wqt + MD;             // 2 MB
    half_t* wvt = wkt + MK;             // 2 MB
    half_t* wot = wvt + MK;             // 8 MB  (total ~42 MB)

    cvt_x <<<2048, 256, 0, stream>>>(x, Xh);
    wtrans<<<10240, 256, 0, stream>>>(wq, wk, wv, wo, wqt, wkt, wvt, wot);
    gemm128<1, half_t><<<384, 256, 0, stream>>>(Xh, wqt, wkt, wvt, Qh, Kh, Vh, 24, 2048);
    rope_k<<<2048, 256, 0, stream>>>(Kh, tc, ts);
    rope_v<<<2048, 256, 0, stream>>>(Vh, Vt, tc, ts);
    attn3 <<<512, 256, 0, stream>>>(Qh, Kh, Vt, Yh);
    gemm128<0, float><<<256, 256, 0, stream>>>(Yh, wot, nullptr, nullptr, out, nullptr, nullptr, 16, 2048);
}

// Round 4
// 126.500 us; speedup vs baseline: 3.1482x; 1.2624x over previous
//
#include <hip/hip_runtime.h>
#include <hip/hip_bf16.h>
#include <stdint.h>

typedef _Float16 half_t;
typedef __attribute__((ext_vector_type(2))) _Float16 h2_t;
typedef __attribute__((ext_vector_type(4))) _Float16 h4_t;
typedef __attribute__((ext_vector_type(8))) _Float16 h8_t;
typedef __attribute__((ext_vector_type(4))) float f32x4;

// async global->LDS, 16B per lane. LDS dest must be wave-uniform base (HW adds lane*16).
__device__ __forceinline__ void gload16(const void* g, void* l) {
    __builtin_amdgcn_global_load_lds(
        (const __attribute__((address_space(1))) uint32_t*)(uintptr_t)g,
        (__attribute__((address_space(3))) uint32_t*)(uint32_t)(uintptr_t)l,
        16, 0, 0);
}

// ---------------- prep: x f32->f16  +  weights f32 [K][N] -> f16 [N][K] ----------------
__global__ __launch_bounds__(256) void prep(const float* __restrict__ x, half_t* __restrict__ xh,
                                            const float* __restrict__ wq, const float* __restrict__ wk,
                                            const float* __restrict__ wv, const float* __restrict__ wo,
                                            half_t* __restrict__ qt, half_t* __restrict__ kt,
                                            half_t* __restrict__ vt, half_t* __restrict__ ot) {
    __shared__ half_t T[32][36];
    const int bx = blockIdx.x;
    if (bx < 2048) {                       // x convert: 2048 blocks x 256 x 8 elems
        int g = (bx * 256 + threadIdx.x) * 8;
        float4 a = *(const float4*)(x + g);
        float4 b = *(const float4*)(x + g + 4);
        h8_t o = {(half_t)a.x,(half_t)a.y,(half_t)a.z,(half_t)a.w,
                  (half_t)b.x,(half_t)b.y,(half_t)b.z,(half_t)b.w};
        *(h8_t*)(xh + g) = o;
        return;
    }
    const int wb = bx - 2048;
    const float* src; half_t* dst; int Nd, t;
    if (wb < 4096)      { src = wq; dst = qt; Nd = 2048; t = wb; }
    else if (wb < 5120) { src = wk; dst = kt; Nd = 512;  t = wb - 4096; }
    else if (wb < 6144) { src = wv; dst = vt; Nd = 512;  t = wb - 5120; }
    else                { src = wo; dst = ot; Nd = 2048; t = wb - 6144; }
    const int K = 2048;
    int nt = Nd >> 5;
    int ti = t / nt, tj = t % nt;          // ti: K-tile, tj: N-tile
    int r  = threadIdx.x >> 3;
    int c4 = (threadIdx.x & 7) << 2;
    float4 v = *(const float4*)(src + (size_t)(ti*32 + r) * Nd + tj*32 + c4);
    T[r][c4+0] = (half_t)v.x; T[r][c4+1] = (half_t)v.y;
    T[r][c4+2] = (half_t)v.z; T[r][c4+3] = (half_t)v.w;
    __syncthreads();
    h4_t o = {T[c4+0][r], T[c4+1][r], T[c4+2][r], T[c4+3][r]};
    *(h4_t*)(dst + (size_t)(tj*32 + r) * K + ti*32 + c4) = o;
}

// ---------------- GEMM: C = A[M][K] @ W^T, W stored [N][K] f16 ----------------
// BM x 128 tile, BK=64, 4 waves (2x2), wave tile (BM/2) x 64.
// LDS XOR-swizzled (16B units within 128B rows): pre-swizzled global source,
// linear global_load_lds dest, swizzled ds_read_b128 (conflict-free).
template<int BM, int QKV, typename CT>
__global__ __launch_bounds__(256) void gemm_t(const half_t* __restrict__ A,
                                              const half_t* __restrict__ Bq,
                                              const half_t* __restrict__ Bk,
                                              const half_t* __restrict__ Bv,
                                              CT* __restrict__ Cq,
                                              half_t* __restrict__ Ck,
                                              half_t* __restrict__ Cv,
                                              int NB, int K) {
    constexpr int MI  = BM / 32;           // acc rows per wave
    constexpr int ACH = BM / 8;            // A chunks (1KB each)
    constexpr int TOT = ACH + 16;          // + B chunks
    constexpr int PW  = TOT / 4;           // chunks per wave
    __shared__ half_t Ah[BM * 64];
    __shared__ half_t Bh[128 * 64];
    const int tid = threadIdx.x, lane = tid & 63, wid = tid >> 6;
    const int lr = lane & 15, lg = lane >> 4;
    const int wm = wid >> 1, wn = wid & 1;
    const int nwg = gridDim.x, bid = blockIdx.x;
    const int swz = (bid & 7) * (nwg >> 3) + (bid >> 3);   // XCD swizzle (nwg % 8 == 0)
    const int bm = swz / NB, bn = swz % NB;
    const int m0 = bm * BM;

    const half_t* W; CT* Cc; int cs, col0;
    if constexpr (QKV) {
        if (bn < 16)      { W = Bq + (size_t)bn * 128 * K;        Cc = Cq;       cs = 2048; col0 = bn * 128; }
        else if (bn < 20) { W = Bk + (size_t)(bn - 16) * 128 * K; Cc = (CT*)Ck;  cs = 512;  col0 = (bn - 16) * 128; }
        else              { W = Bv + (size_t)(bn - 20) * 128 * K; Cc = (CT*)Cv;  cs = 512;  col0 = (bn - 20) * 128; }
    } else {
        W = Bq + (size_t)bn * 128 * K; Cc = Cq; cs = NB * 128; col0 = bn * 128;
    }

    const half_t* Arow = A + (size_t)m0 * K;
    f32x4 acc[MI][4] = {};

    for (int k0 = 0; k0 < K; k0 += 64) {
        #pragma unroll
        for (int c = 0; c < PW; c++) {
            const int chunk = wid * PW + c;                // wave-uniform
            const int o = lane * 16;
            if (chunk < ACH) {
                const int go   = (chunk << 10) + o;
                const int row  = go >> 7;
                const int colb = (go & 127) ^ ((row & 7) << 4);
                gload16(Arow + (size_t)row * K + k0 + (colb >> 1), (char*)Ah + (chunk << 10));
            } else {
                const int go   = ((chunk - ACH) << 10) + o;
                const int row  = go >> 7;
                const int colb = (go & 127) ^ ((row & 7) << 4);
                gload16(W + (size_t)row * K + k0 + (colb >> 1), (char*)Bh + ((chunk - ACH) << 10));
            }
        }
        __syncthreads();
        h8_t af[2][MI], bf[2][4];
        #pragma unroll
        for (int kk = 0; kk < 2; kk++) {
            #pragma unroll
            for (int mi = 0; mi < MI; mi++) {
                const int row = wm * (BM / 2) + mi * 16 + lr;
                const int cb  = (kk * 64 + lg * 16) ^ ((lr & 7) << 4);
                af[kk][mi] = *(const h8_t*)((const char*)Ah + row * 128 + cb);
            }
            #pragma unroll
            for (int ni = 0; ni < 4; ni++) {
                const int row = wn * 64 + ni * 16 + lr;
                const int cb  = (kk * 64 + lg * 16) ^ ((lr & 7) << 4);
                bf[kk][ni] = *(const h8_t*)((const char*)Bh + row * 128 + cb);
            }
        }
        #pragma unroll
        for (int kk = 0; kk < 2; kk++)
            #pragma unroll
            for (int mi = 0; mi < MI; mi++)
                #pragma unroll
                for (int ni = 0; ni < 4; ni++)
                    acc[mi][ni] = __builtin_amdgcn_mfma_f32_16x16x32_f16(af[kk][mi], bf[kk][ni], acc[mi][ni], 0, 0, 0);
        __syncthreads();
    }

    #pragma unroll
    for (int mi = 0; mi < MI; mi++)
        #pragma unroll
        for (int ni = 0; ni < 4; ni++)
            #pragma unroll
            for (int r = 0; r < 4; r++) {
                int row = m0 + wm * (BM / 2) + mi * 16 + lg * 4 + r;
                int col = col0 + wn * 64 + ni * 16 + lr;
                Cc[(size_t)row * cs + col] = (CT)acc[mi][ni][r];
            }
}

// ---------------- RoPE: K in place + V with transpose ----------------
__global__ __launch_bounds__(256) void rope(half_t* __restrict__ Kh, const half_t* __restrict__ Vh,
                                            half_t* __restrict__ Vt, const float* __restrict__ cs,
                                            const float* __restrict__ sn) {
    const int bx = blockIdx.x;
    if (bx < 2048) {                       // K: 2048 rows x 256 pairs
        int gid = bx * 256 + threadIdx.x;
        int row = gid >> 8;
        int pc  = gid & 255;
        int s   = row & 1023;
        int p   = pc & 63;
        float c = cs[s * 64 + p], si = sn[s * 64 + p];
        h2_t v = *(h2_t*)(Kh + (size_t)row * 512 + 2 * pc);
        float x0 = (float)v[0], x1 = (float)v[1];
        h2_t o = {(half_t)(x0 * c - x1 * si), (half_t)(x0 * si + x1 * c)};
        *(h2_t*)(Kh + (size_t)row * 512 + 2 * pc) = o;
        return;
    }
    int gid = (bx - 2048) * 256 + threadIdx.x;
    int col = gid & 2047;                  // b*1024+s (lane-contiguous -> coalesced Vt writes)
    int dp  = gid >> 11;                   // global d-pair
    int s   = col & 1023;
    int p   = dp & 63;
    float c = cs[s * 64 + p], si = sn[s * 64 + p];
    h2_t v = *(const h2_t*)(Vh + (size_t)col * 512 + 2 * dp);
    float x0 = (float)v[0], x1 = (float)v[1];
    Vt[(size_t)(2 * dp)     * 2048 + col] = (half_t)(x0 * c - x1 * si);
    Vt[(size_t)(2 * dp + 1) * 2048 + col] = (half_t)(x0 * si + x1 * c);
}

// ---------------- causal GQA flash attention, 4 waves x 16 q-rows, KVBLK=64 ----------------
__global__ __launch_bounds__(256) void attn3(const half_t* __restrict__ Qh, const half_t* __restrict__ Kh,
                                             const half_t* __restrict__ Vt, half_t* __restrict__ Yh) {
    __shared__ half_t Ktile[64 * 128];   // swizzled: byte = row*256 + (colb ^ ((row&7)<<4))
    __shared__ half_t Vtile[128 * 64];   // swizzled: byte = row*128 + (colb ^ ((row&7)<<4))
    __shared__ half_t Pl[4][16][72];     // per-wave P relayout

    const int tid = threadIdx.x, lane = tid & 63, wid = tid >> 6;
    const int lr = lane & 15, lg = lane >> 4;
    const int bx = blockIdx.x;
    const int g  = bx & 7;               // (b,kvh) group -> same XCD
    const int local = bx >> 3;           // 0..63
    const int b = g >> 2, kvh = g & 3;
    const int h = kvh * 4 + (local & 3);
    const int qt = 15 - (local >> 2);    // longest q-tiles first
    const int nkb = qt + 1;
    const int qbase = qt * 64 + wid * 16;
    const size_t qrow0 = (size_t)(b * 1024 + qbase);
    const size_t kbase = (size_t)b * 1024;

    const float sc = 0.08838834764831845f;   // 1/sqrt(128)
    h8_t qf[4];
    #pragma unroll
    for (int kk = 0; kk < 4; kk++) {
        qf[kk] = *(const h8_t*)(Qh + (qrow0 + lr) * 2048 + h * 128 + kk * 32 + lg * 8);
        qf[kk] = qf[kk] * (half_t)sc;
    }

    float m[4], l[4];
    f32x4 yacc[8] = {};
    #pragma unroll
    for (int r = 0; r < 4; r++) { m[r] = -1e30f; l[r] = 0.f; }

    for (int kb = 0; kb < nkb; kb++) {
        const int j = kb * 64;
        __syncthreads();
        #pragma unroll
        for (int c = 0; c < 4; c++) {
            const int chunk = wid * 4 + c;
            const int o = (chunk << 10) + lane * 16;
            { const int row  = o >> 8;
              const int colb = (o & 255) ^ ((row & 7) << 4);
              gload16(Kh + (kbase + j + row) * 512 + kvh * 128 + (colb >> 1),
                      (char*)Ktile + (chunk << 10)); }
            { const int row  = o >> 7;
              const int colb = (o & 127) ^ ((row & 7) << 4);
              gload16(Vt + (size_t)(kvh * 128 + row) * 2048 + kbase + j + (colb >> 1),
                      (char*)Vtile + (chunk << 10)); }
        }
        __syncthreads();

        f32x4 st[4] = {};
        #pragma unroll
        for (int t = 0; t < 4; t++)
            #pragma unroll
            for (int kk = 0; kk < 4; kk++) {
                const int row = t * 16 + lr;
                const int cb  = (kk * 64 + lg * 16) ^ ((lr & 7) << 4);
                h8_t kf = *(const h8_t*)((const char*)Ktile + row * 256 + cb);
                st[t] = __builtin_amdgcn_mfma_f32_16x16x32_f16(qf[kk], kf, st[t], 0, 0, 0);
            }
        if (kb == nkb - 1) {
            #pragma unroll
            for (int t = 0; t < 4; t++)
                #pragma unroll
                for (int r = 0; r < 4; r++) {
                    int q = qbase + lg * 4 + r;
                    if (j + t * 16 + lr > q) st[t][r] = -1e30f;
                }
        }
        float mb[4];
        #pragma unroll
        for (int r = 0; r < 4; r++)
            mb[r] = fmaxf(fmaxf(st[0][r], st[1][r]), fmaxf(st[2][r], st[3][r]));
        #pragma unroll
        for (int off = 1; off < 16; off <<= 1)
            #pragma unroll
            for (int r = 0; r < 4; r++)
                mb[r] = fmaxf(mb[r], __shfl_xor(mb[r], off));
        float al[4];
        #pragma unroll
        for (int r = 0; r < 4; r++) {
            float mn = fmaxf(m[r], mb[r]);
            al[r] = __expf(m[r] - mn);
            m[r]  = mn;
        }
        float rs[4] = {0.f, 0.f, 0.f, 0.f};
        #pragma unroll
        for (int t = 0; t < 4; t++)
            #pragma unroll
            for (int r = 0; r < 4; r++) {
                float p = __expf(st[t][r] - m[r]);
                st[t][r] = p;
                rs[r] += p;
            }
        #pragma unroll
        for (int off = 1; off < 16; off <<= 1)
            #pragma unroll
            for (int r = 0; r < 4; r++)
                rs[r] += __shfl_xor(rs[r], off);
        #pragma unroll
        for (int r = 0; r < 4; r++) l[r] = l[r] * al[r] + rs[r];
        #pragma unroll
        for (int dt = 0; dt < 8; dt++)
            #pragma unroll
            for (int r = 0; r < 4; r++)
                yacc[dt][r] *= al[r];
        #pragma unroll
        for (int t = 0; t < 4; t++)
            #pragma unroll
            for (int r = 0; r < 4; r++)
                Pl[wid][lg * 4 + r][t * 16 + lr] = (half_t)st[t][r];
        h8_t pa0 = *(const h8_t*)(&Pl[wid][lr][lg * 8]);
        h8_t pa1 = *(const h8_t*)(&Pl[wid][lr][32 + lg * 8]);
        #pragma unroll
        for (int dt = 0; dt < 8; dt++) {
            const int row = dt * 16 + lr;
            const int cb0 = (lg * 16) ^ ((lr & 7) << 4);
            const int cb1 = (64 + lg * 16) ^ ((lr & 7) << 4);
            h8_t v0 = *(const h8_t*)((const char*)Vtile + row * 128 + cb0);
            h8_t v1 = *(const h8_t*)((const char*)Vtile + row * 128 + cb1);
            yacc[dt] = __builtin_amdgcn_mfma_f32_16x16x32_f16(pa0, v0, yacc[dt], 0, 0, 0);
            yacc[dt] = __builtin_amdgcn_mfma_f32_16x16x32_f16(pa1, v1, yacc[dt], 0, 0, 0);
        }
    }

    #pragma unroll
    for (int r = 0; r < 4; r++) l[r] = 1.0f / l[r];
    #pragma unroll
    for (int dt = 0; dt < 8; dt++)
        #pragma unroll
        for (int r = 0; r < 4; r++)
            Yh[(qrow0 + lg * 4 + r) * 2048 + h * 128 + dt * 16 + lr] = (half_t)(yacc[dt][r] * l[r]);
}

extern "C" void kernel_launch(void* const* d_in, const int* in_sizes, int n_in,
                              void* d_out, int out_size, void* d_ws, size_t ws_size,
                              hipStream_t stream) {
    const float* x  = (const float*)d_in[0];
    const float* tc = (const float*)d_in[1];
    const float* ts = (const float*)d_in[2];
    const float* wq = (const float*)d_in[3];
    const float* wk = (const float*)d_in[4];
    const float* wv = (const float*)d_in[5];
    const float* wo = (const float*)d_in[6];
    float* out = (float*)d_out;

    const size_t MD = 2048ull * 2048, MK = 2048ull * 512;
    half_t* Xh  = (half_t*)d_ws;        // 8 MB
    half_t* Qh  = Xh  + MD;             // 8 MB
    half_t* Kh  = Qh  + MD;             // 2 MB
    half_t* Vh  = Kh  + MK;             // 2 MB
    half_t* Vt  = Vh  + MK;             // 2 MB
    half_t* Yh  = Vt  + MK;             // 8 MB
    half_t* wqt = Yh  + MD;             // 8 MB
    half_t* wkt = wqt + MD;             // 2 MB
    half_t* wvt = wkt + MK;             // 2 MB
    half_t* wot = wvt + MK;             // 8 MB  (total ~42 MB)

    prep<<<12288, 256, 0, stream>>>(x, Xh, wq, wk, wv, wo, wqt, wkt, wvt, wot);
    gemm_t<64, 1, half_t><<<768, 256, 0, stream>>>(Xh, wqt, wkt, wvt, Qh, Kh, Vh, 24, 2048);
    rope<<<4096, 256, 0, stream>>>(Kh, Vh, Vt, tc, ts);
    attn3<<<512, 256, 0, stream>>>(Qh, Kh, Vt, Yh);
    gemm_t<64, 0, float><<<512, 256, 0, stream>>>(Yh, wot, nullptr, nullptr, out, nullptr, nullptr, 16, 2048);
}

// Round 5
// 122.493 us; speedup vs baseline: 3.2512x; 1.0327x over previous
//
#include <hip/hip_runtime.h>
#include <hip/hip_bf16.h>
#include <stdint.h>

typedef _Float16 half_t;
typedef __attribute__((ext_vector_type(2))) _Float16 h2_t;
typedef __attribute__((ext_vector_type(4))) _Float16 h4_t;
typedef __attribute__((ext_vector_type(8))) _Float16 h8_t;
typedef __attribute__((ext_vector_type(4))) float f32x4;

// async global->LDS, 16B per lane. LDS dest must be wave-uniform base (HW adds lane*16).
__device__ __forceinline__ void gload16(const void* g, void* l) {
    __builtin_amdgcn_global_load_lds(
        (const __attribute__((address_space(1))) uint32_t*)(uintptr_t)g,
        (__attribute__((address_space(3))) uint32_t*)(uint32_t)(uintptr_t)l,
        16, 0, 0);
}

// ---------------- prep: x f32->f16  +  weights f32 [K][N] -> f16 [N][K] ----------------
__global__ __launch_bounds__(256) void prep(const float* __restrict__ x, half_t* __restrict__ xh,
                                            const float* __restrict__ wq, const float* __restrict__ wk,
                                            const float* __restrict__ wv, const float* __restrict__ wo,
                                            half_t* __restrict__ qt, half_t* __restrict__ kt,
                                            half_t* __restrict__ vt, half_t* __restrict__ ot) {
    __shared__ half_t T[32][36];
    const int bx = blockIdx.x;
    if (bx < 2048) {                       // x convert: 2048 blocks x 256 x 8 elems
        int g = (bx * 256 + threadIdx.x) * 8;
        float4 a = *(const float4*)(x + g);
        float4 b = *(const float4*)(x + g + 4);
        h8_t o = {(half_t)a.x,(half_t)a.y,(half_t)a.z,(half_t)a.w,
                  (half_t)b.x,(half_t)b.y,(half_t)b.z,(half_t)b.w};
        *(h8_t*)(xh + g) = o;
        return;
    }
    const int wb = bx - 2048;
    const float* src; half_t* dst; int Nd, t;
    if (wb < 4096)      { src = wq; dst = qt; Nd = 2048; t = wb; }
    else if (wb < 5120) { src = wk; dst = kt; Nd = 512;  t = wb - 4096; }
    else if (wb < 6144) { src = wv; dst = vt; Nd = 512;  t = wb - 5120; }
    else                { src = wo; dst = ot; Nd = 2048; t = wb - 6144; }
    const int K = 2048;
    int nt = Nd >> 5;
    int ti = t / nt, tj = t % nt;          // ti: K-tile, tj: N-tile
    int r  = threadIdx.x >> 3;
    int c4 = (threadIdx.x & 7) << 2;
    float4 v = *(const float4*)(src + (size_t)(ti*32 + r) * Nd + tj*32 + c4);
    T[r][c4+0] = (half_t)v.x; T[r][c4+1] = (half_t)v.y;
    T[r][c4+2] = (half_t)v.z; T[r][c4+3] = (half_t)v.w;
    __syncthreads();
    h4_t o = {T[c4+0][r], T[c4+1][r], T[c4+2][r], T[c4+3][r]};
    *(h4_t*)(dst + (size_t)(tj*32 + r) * K + ti*32 + c4) = o;
}

// ---------------- GEMM: C = A[M][K] @ W^T, W stored [N][K] f16 ----------------
// BM x 128 tile, BK=64, 4 waves (2x2), wave tile (BM/2) x 64. LDS XOR-swizzled.
template<int BM, int QKV, typename CT>
__global__ __launch_bounds__(256) void gemm_t(const half_t* __restrict__ A,
                                              const half_t* __restrict__ Bq,
                                              const half_t* __restrict__ Bk,
                                              const half_t* __restrict__ Bv,
                                              CT* __restrict__ Cq,
                                              half_t* __restrict__ Ck,
                                              half_t* __restrict__ Cv,
                                              int NB, int K) {
    constexpr int MI  = BM / 32;           // acc rows per wave
    constexpr int ACH = BM / 8;            // A chunks (1KB each)
    constexpr int TOT = ACH + 16;          // + B chunks
    constexpr int PW  = TOT / 4;           // chunks per wave
    __shared__ half_t Ah[BM * 64];
    __shared__ half_t Bh[128 * 64];
    const int tid = threadIdx.x, lane = tid & 63, wid = tid >> 6;
    const int lr = lane & 15, lg = lane >> 4;
    const int wm = wid >> 1, wn = wid & 1;
    const int nwg = gridDim.x, bid = blockIdx.x;
    const int swz = (bid & 7) * (nwg >> 3) + (bid >> 3);   // XCD swizzle (nwg % 8 == 0)
    const int bm = swz / NB, bn = swz % NB;
    const int m0 = bm * BM;

    const half_t* W; CT* Cc; int cs, col0;
    if constexpr (QKV) {
        if (bn < 16)      { W = Bq + (size_t)bn * 128 * K;        Cc = Cq;       cs = 2048; col0 = bn * 128; }
        else if (bn < 20) { W = Bk + (size_t)(bn - 16) * 128 * K; Cc = (CT*)Ck;  cs = 512;  col0 = (bn - 16) * 128; }
        else              { W = Bv + (size_t)(bn - 20) * 128 * K; Cc = (CT*)Cv;  cs = 512;  col0 = (bn - 20) * 128; }
    } else {
        W = Bq + (size_t)bn * 128 * K; Cc = Cq; cs = NB * 128; col0 = bn * 128;
    }

    const half_t* Arow = A + (size_t)m0 * K;
    f32x4 acc[MI][4] = {};

    for (int k0 = 0; k0 < K; k0 += 64) {
        #pragma unroll
        for (int c = 0; c < PW; c++) {
            const int chunk = wid * PW + c;                // wave-uniform
            const int o = lane * 16;
            if (chunk < ACH) {
                const int go   = (chunk << 10) + o;
                const int row  = go >> 7;
                const int colb = (go & 127) ^ ((row & 7) << 4);
                gload16(Arow + (size_t)row * K + k0 + (colb >> 1), (char*)Ah + (chunk << 10));
            } else {
                const int go   = ((chunk - ACH) << 10) + o;
                const int row  = go >> 7;
                const int colb = (go & 127) ^ ((row & 7) << 4);
                gload16(W + (size_t)row * K + k0 + (colb >> 1), (char*)Bh + ((chunk - ACH) << 10));
            }
        }
        __syncthreads();
        h8_t af[2][MI], bf[2][4];
        #pragma unroll
        for (int kk = 0; kk < 2; kk++) {
            #pragma unroll
            for (int mi = 0; mi < MI; mi++) {
                const int row = wm * (BM / 2) + mi * 16 + lr;
                const int cb  = (kk * 64 + lg * 16) ^ ((lr & 7) << 4);
                af[kk][mi] = *(const h8_t*)((const char*)Ah + row * 128 + cb);
            }
            #pragma unroll
            for (int ni = 0; ni < 4; ni++) {
                const int row = wn * 64 + ni * 16 + lr;
                const int cb  = (kk * 64 + lg * 16) ^ ((lr & 7) << 4);
                bf[kk][ni] = *(const h8_t*)((const char*)Bh + row * 128 + cb);
            }
        }
        #pragma unroll
        for (int kk = 0; kk < 2; kk++)
            #pragma unroll
            for (int mi = 0; mi < MI; mi++)
                #pragma unroll
                for (int ni = 0; ni < 4; ni++)
                    acc[mi][ni] = __builtin_amdgcn_mfma_f32_16x16x32_f16(af[kk][mi], bf[kk][ni], acc[mi][ni], 0, 0, 0);
        __syncthreads();
    }

    #pragma unroll
    for (int mi = 0; mi < MI; mi++)
        #pragma unroll
        for (int ni = 0; ni < 4; ni++)
            #pragma unroll
            for (int r = 0; r < 4; r++) {
                int row = m0 + wm * (BM / 2) + mi * 16 + lg * 4 + r;
                int col = col0 + wn * 64 + ni * 16 + lr;
                Cc[(size_t)row * cs + col] = (CT)acc[mi][ni][r];
            }
}

// ---------------- RoPE: K in place + V with transpose ----------------
__global__ __launch_bounds__(256) void rope(half_t* __restrict__ Kh, const half_t* __restrict__ Vh,
                                            half_t* __restrict__ Vt, const float* __restrict__ cs,
                                            const float* __restrict__ sn) {
    const int bx = blockIdx.x;
    if (bx < 2048) {                       // K: 2048 rows x 256 pairs
        int gid = bx * 256 + threadIdx.x;
        int row = gid >> 8;
        int pc  = gid & 255;
        int s   = row & 1023;
        int p   = pc & 63;
        float c = cs[s * 64 + p], si = sn[s * 64 + p];
        h2_t v = *(h2_t*)(Kh + (size_t)row * 512 + 2 * pc);
        float x0 = (float)v[0], x1 = (float)v[1];
        h2_t o = {(half_t)(x0 * c - x1 * si), (half_t)(x0 * si + x1 * c)};
        *(h2_t*)(Kh + (size_t)row * 512 + 2 * pc) = o;
        return;
    }
    int gid = (bx - 2048) * 256 + threadIdx.x;
    int col = gid & 2047;                  // b*1024+s (lane-contiguous -> coalesced Vt writes)
    int dp  = gid >> 11;                   // global d-pair
    int s   = col & 1023;
    int p   = dp & 63;
    float c = cs[s * 64 + p], si = sn[s * 64 + p];
    h2_t v = *(const h2_t*)(Vh + (size_t)col * 512 + 2 * dp);
    float x0 = (float)v[0], x1 = (float)v[1];
    Vt[(size_t)(2 * dp)     * 2048 + col] = (half_t)(x0 * c - x1 * si);
    Vt[(size_t)(2 * dp + 1) * 2048 + col] = (half_t)(x0 * si + x1 * c);
}

// ---------------- causal GQA flash attention, 4 waves x 16 q-rows, KVBLK=64 ----------------
// Balanced pairing: CU gets q-tiles (qt, 15-qt) -> uniform 17 iters/CU.
// Double-buffered K/V (separate LDS symbols), prefetch issued before compute,
// single __syncthreads per iter drains it after compute (T3-minimum 2-phase).
__global__ __launch_bounds__(256) void attn4(const half_t* __restrict__ Qh, const half_t* __restrict__ Kh,
                                             const half_t* __restrict__ Vtg, half_t* __restrict__ Yh) {
    __shared__ half_t K0[64 * 128], K1[64 * 128];  // swizzled rows of 256B
    __shared__ half_t V0[128 * 64], V1[128 * 64];  // swizzled rows of 128B
    __shared__ half_t Pl[4][16][72];               // per-wave P relayout

    const int tid = threadIdx.x, lane = tid & 63, wid = tid >> 6;
    const int lr = lane & 15, lg = lane >> 4;
    const int bx = blockIdx.x;
    const int g  = bx & 7;               // (b,kvh) group -> same XCD
    const int local = bx >> 3;           // 0..63
    const int b = g >> 2, kvh = g & 3;
    const int h = kvh * 4 + (local & 3);
    const int li = local >> 2;           // 0..15
    const int qt = (li < 8) ? (15 - li) : (li - 8);  // CU pair (li, li+32) -> qt sum 15
    const int nkb = qt + 1;
    const int qbase = qt * 64 + wid * 16;
    const size_t qrow0 = (size_t)(b * 1024 + qbase);
    const size_t kbase = (size_t)b * 1024;

    const float sc = 0.08838834764831845f;   // 1/sqrt(128)
    h8_t qf[4];
    #pragma unroll
    for (int kk = 0; kk < 4; kk++) {
        qf[kk] = *(const h8_t*)(Qh + (qrow0 + lr) * 2048 + h * 128 + kk * 32 + lg * 8);
        qf[kk] = qf[kk] * (half_t)sc;
    }

    float m[4], l[4];
    f32x4 yacc[8] = {};
    #pragma unroll
    for (int r = 0; r < 4; r++) { m[r] = -1e30f; l[r] = 0.f; }

    auto stage = [&](half_t* kt, half_t* vb, int kb) {
        const int j = kb * 64;
        #pragma unroll
        for (int c = 0; c < 4; c++) {
            const int chunk = wid * 4 + c;
            const int o = (chunk << 10) + lane * 16;
            { const int row  = o >> 8;
              const int colb = (o & 255) ^ ((row & 7) << 4);
              gload16(Kh + (kbase + j + row) * 512 + kvh * 128 + (colb >> 1),
                      (char*)kt + (chunk << 10)); }
            { const int row  = o >> 7;
              const int colb = (o & 127) ^ ((row & 7) << 4);
              gload16(Vtg + (size_t)(kvh * 128 + row) * 2048 + kbase + j + (colb >> 1),
                      (char*)vb + (chunk << 10)); }
        }
    };

    auto iter = [&](const half_t* kt, const half_t* vb, int kb) {
        const int j = kb * 64;
        f32x4 st[4] = {};
        #pragma unroll
        for (int t = 0; t < 4; t++)
            #pragma unroll
            for (int kk = 0; kk < 4; kk++) {
                const int row = t * 16 + lr;
                const int cb  = (kk * 64 + lg * 16) ^ ((lr & 7) << 4);
                h8_t kf = *(const h8_t*)((const char*)kt + row * 256 + cb);
                st[t] = __builtin_amdgcn_mfma_f32_16x16x32_f16(qf[kk], kf, st[t], 0, 0, 0);
            }
        if (kb == nkb - 1) {             // only the diagonal block needs masking
            #pragma unroll
            for (int t = 0; t < 4; t++)
                #pragma unroll
                for (int r = 0; r < 4; r++) {
                    int q = qbase + lg * 4 + r;
                    if (j + t * 16 + lr > q) st[t][r] = -1e30f;
                }
        }
        float mb[4];
        #pragma unroll
        for (int r = 0; r < 4; r++)
            mb[r] = fmaxf(fmaxf(st[0][r], st[1][r]), fmaxf(st[2][r], st[3][r]));
        #pragma unroll
        for (int off = 1; off < 16; off <<= 1)
            #pragma unroll
            for (int r = 0; r < 4; r++)
                mb[r] = fmaxf(mb[r], __shfl_xor(mb[r], off));
        float al[4];
        #pragma unroll
        for (int r = 0; r < 4; r++) {
            float mn = fmaxf(m[r], mb[r]);
            al[r] = __expf(m[r] - mn);
            m[r]  = mn;
        }
        float rs[4] = {0.f, 0.f, 0.f, 0.f};
        #pragma unroll
        for (int t = 0; t < 4; t++)
            #pragma unroll
            for (int r = 0; r < 4; r++) {
                float p = __expf(st[t][r] - m[r]);
                st[t][r] = p;
                rs[r] += p;
            }
        #pragma unroll
        for (int off = 1; off < 16; off <<= 1)
            #pragma unroll
            for (int r = 0; r < 4; r++)
                rs[r] += __shfl_xor(rs[r], off);
        #pragma unroll
        for (int r = 0; r < 4; r++) l[r] = l[r] * al[r] + rs[r];
        #pragma unroll
        for (int dt = 0; dt < 8; dt++)
            #pragma unroll
            for (int r = 0; r < 4; r++)
                yacc[dt][r] *= al[r];
        #pragma unroll
        for (int t = 0; t < 4; t++)
            #pragma unroll
            for (int r = 0; r < 4; r++)
                Pl[wid][lg * 4 + r][t * 16 + lr] = (half_t)st[t][r];
        h8_t pa0 = *(const h8_t*)(&Pl[wid][lr][lg * 8]);
        h8_t pa1 = *(const h8_t*)(&Pl[wid][lr][32 + lg * 8]);
        #pragma unroll
        for (int dt = 0; dt < 8; dt++) {
            const int row = dt * 16 + lr;
            const int cb0 = (lg * 16) ^ ((lr & 7) << 4);
            const int cb1 = (64 + lg * 16) ^ ((lr & 7) << 4);
            h8_t v0 = *(const h8_t*)((const char*)vb + row * 128 + cb0);
            h8_t v1 = *(const h8_t*)((const char*)vb + row * 128 + cb1);
            yacc[dt] = __builtin_amdgcn_mfma_f32_16x16x32_f16(pa0, v0, yacc[dt], 0, 0, 0);
            yacc[dt] = __builtin_amdgcn_mfma_f32_16x16x32_f16(pa1, v1, yacc[dt], 0, 0, 0);
        }
    };

    stage(K0, V0, 0);
    __syncthreads();                       // drain prologue stage (vmcnt 0 + barrier)
    for (int kb = 0; kb < nkb; kb += 2) {
        if (kb + 1 < nkb) stage(K1, V1, kb + 1);   // prefetch flies during compute
        iter(K0, V0, kb);
        __syncthreads();                   // drain prefetch; all waves done with K0/V0
        if (kb + 1 < nkb) {
            if (kb + 2 < nkb) stage(K0, V0, kb + 2);
            iter(K1, V1, kb + 1);
            __syncthreads();
        }
    }

    #pragma unroll
    for (int r = 0; r < 4; r++) l[r] = 1.0f / l[r];
    #pragma unroll
    for (int dt = 0; dt < 8; dt++)
        #pragma unroll
        for (int r = 0; r < 4; r++)
            Yh[(qrow0 + lg * 4 + r) * 2048 + h * 128 + dt * 16 + lr] = (half_t)(yacc[dt][r] * l[r]);
}

extern "C" void kernel_launch(void* const* d_in, const int* in_sizes, int n_in,
                              void* d_out, int out_size, void* d_ws, size_t ws_size,
                              hipStream_t stream) {
    const float* x  = (const float*)d_in[0];
    const float* tc = (const float*)d_in[1];
    const float* ts = (const float*)d_in[2];
    const float* wq = (const float*)d_in[3];
    const float* wk = (const float*)d_in[4];
    const float* wv = (const float*)d_in[5];
    const float* wo = (const float*)d_in[6];
    float* out = (float*)d_out;

    const size_t MD = 2048ull * 2048, MK = 2048ull * 512;
    half_t* Xh  = (half_t*)d_ws;        // 8 MB
    half_t* Qh  = Xh  + MD;             // 8 MB
    half_t* Kh  = Qh  + MD;             // 2 MB
    half_t* Vh  = Kh  + MK;             // 2 MB
    half_t* Vt  = Vh  + MK;             // 2 MB
    half_t* Yh  = Vt  + MK;             // 8 MB
    half_t* wqt = Yh  + MD;             // 8 MB
    half_t* wkt = wqt + MD;             // 2 MB
    half_t* wvt = wkt + MK;             // 2 MB
    half_t* wot = wvt + MK;             // 8 MB  (total ~42 MB)

    prep<<<12288, 256, 0, stream>>>(x, Xh, wq, wk, wv, wo, wqt, wkt, wvt, wot);
    gemm_t<64, 1, half_t><<<768, 256, 0, stream>>>(Xh, wqt, wkt, wvt, Qh, Kh, Vh, 24, 2048);
    rope<<<4096, 256, 0, stream>>>(Kh, Vh, Vt, tc, ts);
    attn4<<<512, 256, 0, stream>>>(Qh, Kh, Vt, Yh);
    gemm_t<64, 0, float><<<512, 256, 0, stream>>>(Yh, wot, nullptr, nullptr, out, nullptr, nullptr, 16, 2048);
}